// Round 2
// baseline (153957.214 us; speedup 1.0000x reference)
//
#include <hip/hip_runtime.h>
#include <math.h>

// ---------------- problem constants ----------------
// B=12, T=2048, D=260, V=256, R=280, 3D=780
#define NB1 65          // cooperative scan workgroups (65*4 = 260 dims)

// ---------------- workspace layout (float offsets) ----------------
#define OFF_XTAB  0            // [256][780]  soma_w@Wih.T+bih table
#define OFF_KEYS  199680       // [280][260]  l2norm(rel_keys)
#define OFF_SNT   272480       // [260][256]  l2norm(soma_w) transposed
#define OFF_PFCT  339040       // [520][260]  pfc_W transposed
#define OFF_PF    474240       // [2048][12][260] p_f, overlaid later by latf
#define OFF_OUTS  6864000      // [12][2048][260] outs (head doubles as sync flags for k2/k3)
#define OFF_HBUF  13253760     // [2][3120] scan1 h double buffer
#define OFF_LATB  13260000     // [2][3120] scan2 latent double buffer
#define OFF_HMB   13266240     // [2][3120] scan2 h_mono double buffer
#define WS_FLOATS 13272544

// flags: 65 WGs x 32-int stride, two sets (scan1, scan2), at OFF_OUTS (dead
// during both scans; k4 fully rewrites OUTS afterwards)
#define FLAG_STRIDE 32
#define NFLAG_INTS  (2*NB1*FLAG_STRIDE)

// ---------------- output layout (float offsets) ----------------
#define OUT_HF 6291456
#define OUT_HM 6294576
#define OUT_DS 6297696

__device__ inline float block_sum256(float v, float* red) {
  #pragma unroll
  for (int m = 32; m; m >>= 1) v += __shfl_xor(v, m);
  int w = threadIdx.x >> 6;
  __syncthreads();
  if ((threadIdx.x & 63) == 0) red[w] = v;
  __syncthreads();
  return red[0] + red[1] + red[2] + red[3];
}

// contention-free grid barrier: per-WG flag lines + all-to-all polling.
// Producer: fence, sync, release-store my flag = target.
// Consumer: wave 0 polls all 65 flags (one per lane; lane 0 covers flag 64).
__device__ inline void post_and_wait(int* flags, int mywg, int target, bool skip_wait) {
  __threadfence();
  __syncthreads();
  int tid = threadIdx.x;
  if (tid == 0)
    __hip_atomic_store(&flags[mywg*FLAG_STRIDE], target, __ATOMIC_RELEASE, __HIP_MEMORY_SCOPE_AGENT);
  if (!skip_wait) {
    if (tid < 64) {
      for (;;) {
        int v = __hip_atomic_load(&flags[tid*FLAG_STRIDE], __ATOMIC_ACQUIRE, __HIP_MEMORY_SCOPE_AGENT);
        if (tid == 0) {
          int w = __hip_atomic_load(&flags[64*FLAG_STRIDE], __ATOMIC_ACQUIRE, __HIP_MEMORY_SCOPE_AGENT);
          v = v < w ? v : w;
        }
        if (__all(v >= target)) break;
      }
    }
    __syncthreads();
    __threadfence();
  } else {
    __syncthreads();
  }
}

// ============ K0: prep tables (xtab, keys_n, soma_n^T, pfc_W^T) ============
__global__ __launch_bounds__(256) void k0_prep(
    const float* __restrict__ soma_w, const float* __restrict__ gWih,
    const float* __restrict__ gbih, const float* __restrict__ rel_keys,
    const float* __restrict__ pfc_W, float* __restrict__ ws) {
  int bid = blockIdx.x, tid = threadIdx.x;
  __shared__ float row[260];
  __shared__ float red[4];
  if (bid < 256) {                    // xin table row v
    int v = bid;
    row[tid] = soma_w[v*260 + tid];
    if (tid < 4) row[256+tid] = soma_w[v*260 + 256 + tid];
    __syncthreads();
    for (int n = tid; n < 780; n += 256) {
      const float* w = gWih + n*260;
      float acc = gbih[n];
      for (int k = 0; k < 260; ++k) acc += row[k]*w[k];
      ws[OFF_XTAB + v*780 + n] = acc;
    }
  } else if (bid < 536) {             // keys_n row r
    int r = bid - 256;
    row[tid] = rel_keys[r*260 + tid];
    if (tid < 4) row[256+tid] = rel_keys[r*260 + 256 + tid];
    __syncthreads();
    float v0 = row[tid], v1 = (tid < 4) ? row[256+tid] : 0.f;
    float ss = block_sum256(v0*v0 + v1*v1, red);
    float sc = 1.f / fmaxf(sqrtf(ss), 1e-12f);
    ws[OFF_KEYS + r*260 + tid] = v0*sc;
    if (tid < 4) ws[OFF_KEYS + r*260 + 256 + tid] = v1*sc;
  } else if (bid < 792) {             // soma_n transposed, col v
    int v = bid - 536;
    row[tid] = soma_w[v*260 + tid];
    if (tid < 4) row[256+tid] = soma_w[v*260 + 256 + tid];
    __syncthreads();
    float v0 = row[tid], v1 = (tid < 4) ? row[256+tid] : 0.f;
    float ss = block_sum256(v0*v0 + v1*v1, red);
    float sc = 1.f / fmaxf(sqrtf(ss), 1e-12f);
    ws[OFF_SNT + tid*256 + v] = v0*sc;
    if (tid < 4) ws[OFF_SNT + (256+tid)*256 + v] = v1*sc;
  } else {                            // pfc_W transpose row kk
    int kk = bid - 792;               // 0..519
    for (int d = tid; d < 260; d += 256)
      ws[OFF_PFCT + kk*260 + d] = pfc_W[d*520 + kk];
  }
}

// ============ K2: scan1 (GRU over T), 65 WGs, 1 flag-round/step ============
__global__ __launch_bounds__(256) void k2_scan1(
    const int* __restrict__ x, const float* __restrict__ h_f,
    const float* __restrict__ gWhh, const float* __restrict__ gbhh,
    float* __restrict__ ws, int* __restrict__ flags, float* __restrict__ out) {
  int bid = blockIdx.x, tid = threadIdx.x;
  int grp = tid >> 4, l16 = tid & 15;
  int dl = grp & 3, iq = grp >> 2;      // group = (iq, dl): 3 batches x dim dl
  int d = bid*4 + dl;
  int k0 = l16*20;
  float wreg[3][20];
  #pragma unroll
  for (int g = 0; g < 3; ++g) {
    const float* wr = gWhh + (g*260 + d)*260;
    #pragma unroll
    for (int kk = 0; kk < 20; ++kk) {
      int k = k0 + kk;
      wreg[g][kk] = (k < 260) ? wr[k] : 0.f;
    }
  }
  __shared__ float h_lds[12][320];
  __shared__ float gl[4][12][3];
  __shared__ float bhh_l[4][3];
  for (int idx = tid; idx < 12*320; idx += 256) ((float*)h_lds)[idx] = 0.f;
  if (tid < 12) {
    int dl2 = tid / 3, g2 = tid - dl2*3;
    bhh_l[dl2][g2] = gbhh[g2*260 + bid*4 + dl2];
  }
  float* hbuf = ws + OFF_HBUF;
  float* pf   = ws + OFF_PF;
  const float* xtab = ws + OFF_XTAB;
  __syncthreads();
  for (int t = 0; t < 2048; ++t) {
    int cur = t & 1;
    const float* hsrc = (t == 0) ? h_f : (hbuf + cur*3120);
    for (int idx = tid; idx < 780; idx += 256) {
      int i = idx / 65, j = idx - i*65;
      ((float4*)&h_lds[i][0])[j] = ((const float4*)(hsrc + i*260))[j];
    }
    __syncthreads();
    #pragma unroll
    for (int i3 = 0; i3 < 3; ++i3) {
      int i = iq*3 + i3;
      float a0 = 0, a1 = 0, a2 = 0;
      const float* hp = &h_lds[i][k0];
      #pragma unroll
      for (int kk = 0; kk < 20; ++kk) {
        float hv = hp[kk];
        a0 += wreg[0][kk]*hv; a1 += wreg[1][kk]*hv; a2 += wreg[2][kk]*hv;
      }
      #pragma unroll
      for (int m = 8; m; m >>= 1) {
        a0 += __shfl_xor(a0, m); a1 += __shfl_xor(a1, m); a2 += __shfl_xor(a2, m);
      }
      if (l16 == 0) { gl[dl][i][0] = a0; gl[dl][i][1] = a1; gl[dl][i][2] = a2; }
    }
    __syncthreads();
    if (tid < 48) {
      int dl2 = tid / 12, i = tid - dl2*12;
      int dd = bid*4 + dl2;
      int xi = x[i*2048 + t];
      const float* xrow = xtab + xi*780;
      float xr = xrow[dd], xz = xrow[260+dd], xn = xrow[520+dd];
      float hr = gl[dl2][i][0] + bhh_l[dl2][0];
      float hz = gl[dl2][i][1] + bhh_l[dl2][1];
      float hn = gl[dl2][i][2] + bhh_l[dl2][2];
      float rg = 1.f/(1.f + expf(-(xr+hr)));
      float zg = 1.f/(1.f + expf(-(xz+hz)));
      float ng = tanhf(xn + rg*hn);
      float hprev = h_lds[i][dd];
      float hnew = (1.f - zg)*ng + zg*hprev;
      hbuf[(cur^1)*3120 + i*260 + dd] = hnew;
      pf[(t*12 + i)*260 + dd] = hnew;
      if (t == 2047) out[OUT_HF + i*260 + dd] = hnew;
    }
    post_and_wait(flags, bid, t+1, t == 2047);
  }
}

// ============ K3: scan2 recurrent core (dynamic loop), 65 WGs ============
__global__ __launch_bounds__(256) void k3_scan2(
    const float* __restrict__ h_mono, const float* __restrict__ wWih,
    const float* __restrict__ wWhh, const float* __restrict__ wbih,
    const float* __restrict__ wbhh, const float* __restrict__ vgW,
    const float* __restrict__ vgb, const int* __restrict__ surprise,
    const int* __restrict__ dsteps, float* __restrict__ ws,
    int* __restrict__ flags, float* __restrict__ out) {
  int bid = blockIdx.x, tid = threadIdx.x;
  int grp = tid >> 4, l16 = tid & 15;
  int dl = grp & 3, iq = grp >> 2;
  int d = bid*4 + dl;
  int k0 = l16*20;
  float wi[3][20], wh[3][20];
  #pragma unroll
  for (int g = 0; g < 3; ++g) {
    const float* w1 = wWih + (g*260 + d)*260;
    const float* w2 = wWhh + (g*260 + d)*260;
    #pragma unroll
    for (int kk = 0; kk < 20; ++kk) {
      int k = k0 + kk;
      wi[g][kk] = (k < 260) ? w1[k] : 0.f;
      wh[g][kk] = (k < 260) ? w2[k] : 0.f;
    }
  }
  __shared__ float lat[12][320];
  __shared__ float hm[12][320];
  __shared__ float gl6[4][12][6];
  __shared__ float vol_l[12];
  __shared__ float vg_l[320];
  __shared__ float bih_l[4][3], bhh_l[4][3];
  for (int idx = tid; idx < 12*320; idx += 256) { ((float*)lat)[idx] = 0.f; ((float*)hm)[idx] = 0.f; }
  for (int idx = tid; idx < 320; idx += 256) vg_l[idx] = (idx < 260) ? vgW[idx] : 0.f;
  if (tid < 12) {
    int dl2 = tid / 3, g2 = tid - dl2*3;
    bih_l[dl2][g2] = wbih[g2*260 + bid*4 + dl2];
    bhh_l[dl2][g2] = wbhh[g2*260 + bid*4 + dl2];
  }
  int ds = dsteps[0]; if (ds < 1) ds = 1;
  float sb = logf(fmaxf(1.f, (float)surprise[0]));
  float vgb_sb = vgb[0] + sb;
  float will_r = 0.f, cost_r = 0.f;
  const float costfac = 0.12f/2048.f;
  float* pf   = ws + OFF_PF;
  float* latb = ws + OFF_LATB;
  float* hmb  = ws + OFF_HMB;
  int p = 0;
  __syncthreads();
  for (int t = 0; t < 2048; ++t) {
    const float* lsrc = pf + t*3120;
    const float* hsrc = (t == 0) ? h_mono : (hmb + p*3120);
    for (int idx = tid; idx < 780; idx += 256) {
      int i = idx / 65, j = idx - i*65;
      ((float4*)&lat[i][0])[j] = ((const float4*)(lsrc + i*260))[j];
      ((float4*)&hm[i][0])[j]  = ((const float4*)(hsrc + i*260))[j];
    }
    __syncthreads();
    for (int s = 0; s < ds; ++s) {
      // vol (redundant in every WG, identical results)
      if (grp < 12) {
        int i = grp;
        float pv = 0;
        const float* lp = &lat[i][k0];
        #pragma unroll
        for (int kk = 0; kk < 20; ++kk) pv += vg_l[k0+kk]*lp[kk];
        #pragma unroll
        for (int m = 8; m; m >>= 1) pv += __shfl_xor(pv, m);
        if (l16 == 0) vol_l[i] = 1.f/(1.f + expf(-(pv + vgb_sb)));
      }
      __syncthreads();
      if (tid == 0) {
        float vs = 0;
        #pragma unroll
        for (int i = 0; i < 12; ++i) vs += vol_l[i];
        float vm = vs * (1.f/12.f);
        will_r += vm;
        cost_r += vm * costfac;
      }
      // grucell partial dots for our 4 dims
      #pragma unroll
      for (int i3 = 0; i3 < 3; ++i3) {
        int i = iq*3 + i3;
        float a0=0,a1=0,a2=0,b0=0,b1=0,b2=0;
        const float* lp = &lat[i][k0];
        const float* hp = &hm[i][k0];
        #pragma unroll
        for (int kk = 0; kk < 20; ++kk) {
          float lv = lp[kk], hv = hp[kk];
          a0 += wi[0][kk]*lv; a1 += wi[1][kk]*lv; a2 += wi[2][kk]*lv;
          b0 += wh[0][kk]*hv; b1 += wh[1][kk]*hv; b2 += wh[2][kk]*hv;
        }
        #pragma unroll
        for (int m = 8; m; m >>= 1) {
          a0 += __shfl_xor(a0,m); a1 += __shfl_xor(a1,m); a2 += __shfl_xor(a2,m);
          b0 += __shfl_xor(b0,m); b1 += __shfl_xor(b1,m); b2 += __shfl_xor(b2,m);
        }
        if (l16 == 0) {
          gl6[dl][i][0]=a0; gl6[dl][i][1]=a1; gl6[dl][i][2]=a2;
          gl6[dl][i][3]=b0; gl6[dl][i][4]=b1; gl6[dl][i][5]=b2;
        }
      }
      __syncthreads();
      if (tid < 48) {
        int dl2 = tid / 12, i = tid - dl2*12;
        int dd = bid*4 + dl2;
        float xr = gl6[dl2][i][0] + bih_l[dl2][0];
        float xz = gl6[dl2][i][1] + bih_l[dl2][1];
        float xn = gl6[dl2][i][2] + bih_l[dl2][2];
        float hr = gl6[dl2][i][3] + bhh_l[dl2][0];
        float hz = gl6[dl2][i][4] + bhh_l[dl2][1];
        float hn = gl6[dl2][i][5] + bhh_l[dl2][2];
        float rg = 1.f/(1.f + expf(-(xr+hr)));
        float zg = 1.f/(1.f + expf(-(xz+hz)));
        float ng = tanhf(xn + rg*hn);
        float hmold = hm[i][dd];
        float hmnew = (1.f - zg)*ng + zg*hmold;
        float latnew = lat[i][dd] + hmnew * vol_l[i];
        hmb[(p^1)*3120 + i*260 + dd] = hmnew;
        latb[(p^1)*3120 + i*260 + dd] = latnew;
        if (s == ds-1) {
          pf[(t*12 + i)*260 + dd] = latnew;   // latf overlays p_f[t] (read 3 rounds earlier)
          if (t == 2047) out[OUT_HM + i*260 + dd] = hmnew;
        }
      }
      post_and_wait(flags, bid, t*ds + s + 1, (t == 2047) && (s == ds-1));
      p ^= 1;
      if (s < ds-1) {
        const float* ls2 = latb + p*3120;
        const float* hs2 = hmb + p*3120;
        for (int idx = tid; idx < 780; idx += 256) {
          int i = idx / 65, j = idx - i*65;
          ((float4*)&lat[i][0])[j] = ((const float4*)(ls2 + i*260))[j];
          ((float4*)&hm[i][0])[j]  = ((const float4*)(hs2 + i*260))[j];
        }
        __syncthreads();
      }
    }
  }
  if (bid == 0 && tid == 0) {
    out[OUT_DS]   = (float)dsteps[0];
    out[OUT_DS+1] = cost_r;
    out[OUT_DS+2] = will_r / (2048.f * (float)ds);
  }
}

// ============ K4: per-t tail (attention + pfc + LN + GELU), parallel over t ============
__global__ __launch_bounds__(256) void k4_tail(
    const float* __restrict__ rel_vals, const float* __restrict__ pfc_b,
    const float* __restrict__ pfc_g, const float* __restrict__ pfc_beta,
    float* __restrict__ ws) {
  int t = blockIdx.x, tid = threadIdx.x;
  int tg = tid >> 4, l16 = tid & 15;
  __shared__ float lat[12][260];
  __shared__ float sc[12][280];
  __shared__ float ctx[12][260];
  __shared__ float zb[12][260];
  __shared__ float qinv[12];
  __shared__ float mu[12], rstd[12];
  const float* lsrc = ws + OFF_PF + t*3120;   // latf
  for (int idx = tid; idx < 780; idx += 256)
    ((float4*)lat)[idx] = ((const float4*)lsrc)[idx];
  __syncthreads();
  if (tg < 12) {
    float ss = 0;
    for (int k = l16; k < 260; k += 16) { float v = lat[tg][k]; ss += v*v; }
    #pragma unroll
    for (int m = 8; m; m >>= 1) ss += __shfl_xor(ss, m);
    if (l16 == 0) qinv[tg] = 1.f / fmaxf(sqrtf(ss), 1e-12f);
  }
  __syncthreads();
  for (int r = tid; r < 280; r += 256) {
    const float* kn = ws + OFF_KEYS + r*260;
    float acc[12];
    #pragma unroll
    for (int i = 0; i < 12; ++i) acc[i] = 0.f;
    for (int k = 0; k < 260; ++k) {
      float kv = kn[k];
      #pragma unroll
      for (int i = 0; i < 12; ++i) acc[i] += lat[i][k]*kv;
    }
    #pragma unroll
    for (int i = 0; i < 12; ++i) sc[i][r] = acc[i]*qinv[i];
  }
  __syncthreads();
  if (tg < 12) {
    float mx = -1e30f;
    for (int r = l16; r < 280; r += 16) mx = fmaxf(mx, sc[tg][r]);
    #pragma unroll
    for (int m = 8; m; m >>= 1) mx = fmaxf(mx, __shfl_xor(mx, m));
    float sum = 0;
    for (int r = l16; r < 280; r += 16) { float e = expf(sc[tg][r]-mx); sc[tg][r] = e; sum += e; }
    #pragma unroll
    for (int m = 8; m; m >>= 1) sum += __shfl_xor(sum, m);
    float inv = 1.f/sum;
    for (int r = l16; r < 280; r += 16) sc[tg][r] *= inv;
  }
  __syncthreads();
  for (int dd = tid; dd < 260; dd += 256) {
    float acc[12];
    #pragma unroll
    for (int i = 0; i < 12; ++i) acc[i] = 0.f;
    for (int r = 0; r < 280; ++r) {
      float rv = rel_vals[r*260 + dd];
      #pragma unroll
      for (int i = 0; i < 12; ++i) acc[i] += sc[i][r]*rv;
    }
    #pragma unroll
    for (int i = 0; i < 12; ++i) ctx[i][dd] = acc[i];
  }
  __syncthreads();
  for (int dd = tid; dd < 260; dd += 256) {
    float acc[12];
    float pb = pfc_b[dd];
    #pragma unroll
    for (int i = 0; i < 12; ++i) acc[i] = pb;
    const float* wt = ws + OFF_PFCT;
    for (int k = 0; k < 260; ++k) {
      float w1 = wt[k*260 + dd];
      #pragma unroll
      for (int i = 0; i < 12; ++i) acc[i] += lat[i][k]*w1;
    }
    for (int k = 0; k < 260; ++k) {
      float w2 = wt[(260+k)*260 + dd];
      #pragma unroll
      for (int i = 0; i < 12; ++i) acc[i] += ctx[i][k]*w2;
    }
    #pragma unroll
    for (int i = 0; i < 12; ++i) zb[i][dd] = acc[i];
  }
  __syncthreads();
  if (tg < 12) {
    float s1 = 0, s2 = 0;
    for (int k = l16; k < 260; k += 16) { float v = zb[tg][k]; s1 += v; s2 += v*v; }
    #pragma unroll
    for (int m = 8; m; m >>= 1) { s1 += __shfl_xor(s1,m); s2 += __shfl_xor(s2,m); }
    if (l16 == 0) {
      float mm = s1*(1.f/260.f);
      mu[tg] = mm;
      rstd[tg] = rsqrtf(s2*(1.f/260.f) - mm*mm + 1e-5f);
    }
  }
  __syncthreads();
  for (int dd = tid; dd < 260; dd += 256) {
    float g = pfc_g[dd], b = pfc_beta[dd];
    #pragma unroll
    for (int i = 0; i < 12; ++i) {
      float v = (zb[i][dd]-mu[i])*rstd[i]*g + b;
      float ge = 0.5f*v*(1.f + erff(v*0.70710678118654752f));
      ws[OFF_OUTS + (i*2048 + t)*260 + dd] = ge;
    }
  }
}

// ============ K5: fused LN + logits GEMM (8 rows per WG) ============
__global__ __launch_bounds__(256) void k5_logits(
    const float* __restrict__ on_g, const float* __restrict__ on_b,
    const float* __restrict__ gain, float* __restrict__ ws,
    float* __restrict__ out) {
  int bid = blockIdx.x, tid = threadIdx.x;
  __shared__ float nl[8][260];
  __shared__ float red[4];
  float gn = gain[0];
  float og0 = on_g[tid], ob0 = on_b[tid];
  float og1 = (tid < 4) ? on_g[256+tid] : 0.f;
  float ob1 = (tid < 4) ? on_b[256+tid] : 0.f;
  for (int ii = 0; ii < 8; ++ii) {
    int m = bid*8 + ii;
    const float* row = ws + OFF_OUTS + m*260;
    float v0 = row[tid];
    float v1 = (tid < 4) ? row[256+tid] : 0.f;
    float s1 = block_sum256(v0 + v1, red);
    float s2 = block_sum256(v0*v0 + v1*v1, red);
    float mm = s1*(1.f/260.f);
    float rs = rsqrtf(s2*(1.f/260.f) - mm*mm + 1e-5f);
    nl[ii][tid] = (v0-mm)*rs*og0 + ob0;
    if (tid < 4) nl[ii][256+tid] = (v1-mm)*rs*og1 + ob1;
  }
  __syncthreads();
  float acc[8];
  #pragma unroll
  for (int ii = 0; ii < 8; ++ii) acc[ii] = 0.f;
  const float* st = ws + OFF_SNT;
  for (int k = 0; k < 260; ++k) {
    float wv = st[k*256 + tid];
    #pragma unroll
    for (int ii = 0; ii < 8; ++ii) acc[ii] += nl[ii][k]*wv;
  }
  #pragma unroll
  for (int ii = 0; ii < 8; ++ii)
    out[(bid*8 + ii)*256 + tid] = acc[ii]*gn;
}

// ============================ launch ============================
extern "C" void kernel_launch(void* const* d_in, const int* in_sizes, int n_in,
                              void* d_out, int out_size, void* d_ws, size_t ws_size,
                              hipStream_t stream) {
  const int*   x        = (const int*)  d_in[0];
  const float* h_f      = (const float*)d_in[1];
  const float* h_mono   = (const float*)d_in[2];
  const int*   surprise = (const int*)  d_in[3];
  const int*   dsteps   = (const int*)  d_in[4];
  const float* soma_w   = (const float*)d_in[5];
  const float* gWih     = (const float*)d_in[6];
  const float* gWhh     = (const float*)d_in[7];
  const float* gbih     = (const float*)d_in[8];
  const float* gbhh     = (const float*)d_in[9];
  const float* wWih     = (const float*)d_in[10];
  const float* wWhh     = (const float*)d_in[11];
  const float* wbih     = (const float*)d_in[12];
  const float* wbhh     = (const float*)d_in[13];
  const float* vgW      = (const float*)d_in[14];
  const float* vgb      = (const float*)d_in[15];
  const float* rel_keys = (const float*)d_in[16];
  const float* rel_vals = (const float*)d_in[17];
  const float* pfc_W    = (const float*)d_in[18];
  const float* pfc_b    = (const float*)d_in[19];
  const float* pfc_g    = (const float*)d_in[20];
  const float* pfc_beta = (const float*)d_in[21];
  const float* on_g     = (const float*)d_in[22];
  const float* on_b     = (const float*)d_in[23];
  const float* gain     = (const float*)d_in[24];
  float* out = (float*)d_out;
  float* ws  = (float*)d_ws;
  if (ws_size < (size_t)WS_FLOATS * sizeof(float)) return;  // fail loudly (poisoned out)
  int* flags1 = (int*)(ws + OFF_OUTS);          // dead region during scans
  int* flags2 = flags1 + NB1*FLAG_STRIDE;
  hipMemsetAsync(flags1, 0, NFLAG_INTS*sizeof(int), stream);
  k0_prep  <<<1312, 256, 0, stream>>>(soma_w, gWih, gbih, rel_keys, pfc_W, ws);
  k2_scan1 <<<NB1, 256, 0, stream>>>(x, h_f, gWhh, gbhh, ws, flags1, out);
  k3_scan2 <<<NB1, 256, 0, stream>>>(h_mono, wWih, wWhh, wbih, wbhh, vgW, vgb,
                                     surprise, dsteps, ws, flags2, out);
  k4_tail  <<<2048, 256, 0, stream>>>(rel_vals, pfc_b, pfc_g, pfc_beta, ws);
  k5_logits<<<3072, 256, 0, stream>>>(on_g, on_b, gain, ws, out);
}

// Round 3
// 89822.290 us; speedup vs baseline: 1.7140x; 1.7140x over previous
//
#include <hip/hip_runtime.h>
#include <math.h>

// ---------------- problem constants ----------------
// B=12, T=2048, D=260, V=256, R=280, 3D=780
#define NB1 65          // cooperative scan workgroups (65*4 = 260 dims)

// ---------------- workspace layout (float offsets) ----------------
#define OFF_XTAB  0            // [256][780]  soma_w@Wih.T+bih table
#define OFF_KEYS  199680       // [280][260]  l2norm(rel_keys)
#define OFF_SNT   272480       // [260][256]  l2norm(soma_w) transposed
#define OFF_PFCT  339040       // [520][260]  pfc_W transposed
#define OFF_PF    474240       // [2048][12][260] p_f, overlaid later by latf
#define OFF_OUTS  6864000      // [12][2048][260] outs (head doubles as sync flags for k2/k3)
#define OFF_HBUF  13253760     // [2][3120] scan1 h double buffer
#define OFF_LATB  13260000     // [2][3120] scan2 latent double buffer
#define OFF_HMB   13266240     // [2][3120] scan2 h_mono double buffer
#define WS_FLOATS 13272544

// flags: 65 WGs x 32-int stride, two sets (scan1, scan2), at OFF_OUTS (dead
// during both scans; k4 fully rewrites OUTS afterwards)
#define FLAG_STRIDE 32
#define NFLAG_INTS  (2*NB1*FLAG_STRIDE)

// ---------------- output layout (float offsets) ----------------
#define OUT_HF 6291456
#define OUT_HM 6294576
#define OUT_DS 6297696

// write-through (coherence-point) scalar ops: relaxed agent atomics emit NO
// buffer_wbl2/buffer_inv cache maintenance — per-op coherent via sc0/sc1.
__device__ inline void st_wt(float* p, float v) {
  __hip_atomic_store(p, v, __ATOMIC_RELAXED, __HIP_MEMORY_SCOPE_AGENT);
}
__device__ inline float ld_wt(const float* p) {
  return __hip_atomic_load(p, __ATOMIC_RELAXED, __HIP_MEMORY_SCOPE_AGENT);
}

__device__ inline float block_sum256(float v, float* red) {
  #pragma unroll
  for (int m = 32; m; m >>= 1) v += __shfl_xor(v, m);
  int w = threadIdx.x >> 6;
  __syncthreads();
  if ((threadIdx.x & 63) == 0) red[w] = v;
  __syncthreads();
  return red[0] + red[1] + red[2] + red[3];
}

// contention-free, maintenance-op-free grid barrier.
// __syncthreads() drains each wave's vmcnt (compiler emits full s_waitcnt
// before s_barrier), so the prior write-through data stores are acked at the
// coherence point before the flag store issues. Readers poll with relaxed
// loads (no buffer_inv) and then load data from the same coherence point.
__device__ inline void post_and_wait(int* flags, int mywg, int target, bool skip_wait) {
  __syncthreads();
  int tid = threadIdx.x;
  if (tid == 0) {
    asm volatile("s_waitcnt vmcnt(0)" ::: "memory");
    __hip_atomic_store(&flags[mywg*FLAG_STRIDE], target, __ATOMIC_RELAXED, __HIP_MEMORY_SCOPE_AGENT);
  }
  if (!skip_wait) {
    if (tid < 64) {
      int fi = tid*FLAG_STRIDE;
      for (;;) {
        int v = __hip_atomic_load(&flags[fi], __ATOMIC_RELAXED, __HIP_MEMORY_SCOPE_AGENT);
        if (tid == 0) {
          int w = __hip_atomic_load(&flags[64*FLAG_STRIDE], __ATOMIC_RELAXED, __HIP_MEMORY_SCOPE_AGENT);
          v = v < w ? v : w;
        }
        if (__all(v >= target)) break;
      }
    }
    __syncthreads();
  }
}

// ============ K0: prep tables (xtab, keys_n, soma_n^T, pfc_W^T) ============
__global__ __launch_bounds__(256) void k0_prep(
    const float* __restrict__ soma_w, const float* __restrict__ gWih,
    const float* __restrict__ gbih, const float* __restrict__ rel_keys,
    const float* __restrict__ pfc_W, float* __restrict__ ws) {
  int bid = blockIdx.x, tid = threadIdx.x;
  __shared__ float row[260];
  __shared__ float red[4];
  if (bid < 256) {                    // xin table row v
    int v = bid;
    row[tid] = soma_w[v*260 + tid];
    if (tid < 4) row[256+tid] = soma_w[v*260 + 256 + tid];
    __syncthreads();
    for (int n = tid; n < 780; n += 256) {
      const float* w = gWih + n*260;
      float acc = gbih[n];
      for (int k = 0; k < 260; ++k) acc += row[k]*w[k];
      ws[OFF_XTAB + v*780 + n] = acc;
    }
  } else if (bid < 536) {             // keys_n row r
    int r = bid - 256;
    row[tid] = rel_keys[r*260 + tid];
    if (tid < 4) row[256+tid] = rel_keys[r*260 + 256 + tid];
    __syncthreads();
    float v0 = row[tid], v1 = (tid < 4) ? row[256+tid] : 0.f;
    float ss = block_sum256(v0*v0 + v1*v1, red);
    float sc = 1.f / fmaxf(sqrtf(ss), 1e-12f);
    ws[OFF_KEYS + r*260 + tid] = v0*sc;
    if (tid < 4) ws[OFF_KEYS + r*260 + 256 + tid] = v1*sc;
  } else if (bid < 792) {             // soma_n transposed, col v
    int v = bid - 536;
    row[tid] = soma_w[v*260 + tid];
    if (tid < 4) row[256+tid] = soma_w[v*260 + 256 + tid];
    __syncthreads();
    float v0 = row[tid], v1 = (tid < 4) ? row[256+tid] : 0.f;
    float ss = block_sum256(v0*v0 + v1*v1, red);
    float sc = 1.f / fmaxf(sqrtf(ss), 1e-12f);
    ws[OFF_SNT + tid*256 + v] = v0*sc;
    if (tid < 4) ws[OFF_SNT + (256+tid)*256 + v] = v1*sc;
  } else {                            // pfc_W transpose row kk
    int kk = bid - 792;               // 0..519
    for (int d = tid; d < 260; d += 256)
      ws[OFF_PFCT + kk*260 + d] = pfc_W[d*520 + kk];
  }
}

// ============ K2: scan1 (GRU over T), 65 WGs, 1 flag-round/step ============
__global__ __launch_bounds__(256) void k2_scan1(
    const int* __restrict__ x, const float* __restrict__ h_f,
    const float* __restrict__ gWhh, const float* __restrict__ gbhh,
    float* __restrict__ ws, int* __restrict__ flags, float* __restrict__ out) {
  int bid = blockIdx.x, tid = threadIdx.x;
  int grp = tid >> 4, l16 = tid & 15;
  int dl = grp & 3, iq = grp >> 2;      // group = (iq, dl): 3 batches x dim dl
  int d = bid*4 + dl;
  int k0 = l16*20;
  float wreg[3][20];
  #pragma unroll
  for (int g = 0; g < 3; ++g) {
    const float* wr = gWhh + (g*260 + d)*260;
    #pragma unroll
    for (int kk = 0; kk < 20; ++kk) {
      int k = k0 + kk;
      wreg[g][kk] = (k < 260) ? wr[k] : 0.f;
    }
  }
  __shared__ float h_lds[12][320];
  __shared__ float gl[4][12][3];
  __shared__ float bhh_l[4][3];
  for (int idx = tid; idx < 12*320; idx += 256) ((float*)h_lds)[idx] = 0.f;
  if (tid < 12) {
    int dl2 = tid / 3, g2 = tid - dl2*3;
    bhh_l[dl2][g2] = gbhh[g2*260 + bid*4 + dl2];
  }
  float* hbuf = ws + OFF_HBUF;
  float* pf   = ws + OFF_PF;
  const float* xtab = ws + OFF_XTAB;
  __syncthreads();
  for (int t = 0; t < 2048; ++t) {
    int cur = t & 1;
    if (t == 0) {
      for (int idx = tid; idx < 780; idx += 256) {
        int i = idx / 65, j = idx - i*65;
        ((float4*)&h_lds[i][0])[j] = ((const float4*)(h_f + i*260))[j];
      }
    } else {
      const float* hs = hbuf + cur*3120;
      for (int idx = tid; idx < 3120; idx += 256) {
        int i = idx / 260, dd = idx - i*260;
        h_lds[i][dd] = ld_wt(hs + idx);
      }
    }
    __syncthreads();
    #pragma unroll
    for (int i3 = 0; i3 < 3; ++i3) {
      int i = iq*3 + i3;
      float a0 = 0, a1 = 0, a2 = 0;
      const float* hp = &h_lds[i][k0];
      #pragma unroll
      for (int kk = 0; kk < 20; ++kk) {
        float hv = hp[kk];
        a0 += wreg[0][kk]*hv; a1 += wreg[1][kk]*hv; a2 += wreg[2][kk]*hv;
      }
      #pragma unroll
      for (int m = 8; m; m >>= 1) {
        a0 += __shfl_xor(a0, m); a1 += __shfl_xor(a1, m); a2 += __shfl_xor(a2, m);
      }
      if (l16 == 0) { gl[dl][i][0] = a0; gl[dl][i][1] = a1; gl[dl][i][2] = a2; }
    }
    __syncthreads();
    if (tid < 48) {
      int dl2 = tid / 12, i = tid - dl2*12;
      int dd = bid*4 + dl2;
      int xi = x[i*2048 + t];
      const float* xrow = xtab + xi*780;
      float xr = xrow[dd], xz = xrow[260+dd], xn = xrow[520+dd];
      float hr = gl[dl2][i][0] + bhh_l[dl2][0];
      float hz = gl[dl2][i][1] + bhh_l[dl2][1];
      float hn = gl[dl2][i][2] + bhh_l[dl2][2];
      float rg = 1.f/(1.f + expf(-(xr+hr)));
      float zg = 1.f/(1.f + expf(-(xz+hz)));
      float ng = tanhf(xn + rg*hn);
      float hprev = h_lds[i][dd];
      float hnew = (1.f - zg)*ng + zg*hprev;
      st_wt(hbuf + (cur^1)*3120 + i*260 + dd, hnew);
      pf[(t*12 + i)*260 + dd] = hnew;
      if (t == 2047) out[OUT_HF + i*260 + dd] = hnew;
    }
    post_and_wait(flags, bid, t+1, t == 2047);
  }
}

// ============ K3: scan2 recurrent core (dynamic loop), 65 WGs ============
__global__ __launch_bounds__(256) void k3_scan2(
    const float* __restrict__ h_mono, const float* __restrict__ wWih,
    const float* __restrict__ wWhh, const float* __restrict__ wbih,
    const float* __restrict__ wbhh, const float* __restrict__ vgW,
    const float* __restrict__ vgb, const int* __restrict__ surprise,
    const int* __restrict__ dsteps, float* __restrict__ ws,
    int* __restrict__ flags, float* __restrict__ out) {
  int bid = blockIdx.x, tid = threadIdx.x;
  int grp = tid >> 4, l16 = tid & 15;
  int dl = grp & 3, iq = grp >> 2;
  int d = bid*4 + dl;
  int k0 = l16*20;
  float wi[3][20], wh[3][20];
  #pragma unroll
  for (int g = 0; g < 3; ++g) {
    const float* w1 = wWih + (g*260 + d)*260;
    const float* w2 = wWhh + (g*260 + d)*260;
    #pragma unroll
    for (int kk = 0; kk < 20; ++kk) {
      int k = k0 + kk;
      wi[g][kk] = (k < 260) ? w1[k] : 0.f;
      wh[g][kk] = (k < 260) ? w2[k] : 0.f;
    }
  }
  __shared__ float lat[12][320];
  __shared__ float hm[12][320];
  __shared__ float gl6[4][12][6];
  __shared__ float vol_l[12];
  __shared__ float vg_l[320];
  __shared__ float bih_l[4][3], bhh_l[4][3];
  for (int idx = tid; idx < 12*320; idx += 256) { ((float*)lat)[idx] = 0.f; ((float*)hm)[idx] = 0.f; }
  for (int idx = tid; idx < 320; idx += 256) vg_l[idx] = (idx < 260) ? vgW[idx] : 0.f;
  if (tid < 12) {
    int dl2 = tid / 3, g2 = tid - dl2*3;
    bih_l[dl2][g2] = wbih[g2*260 + bid*4 + dl2];
    bhh_l[dl2][g2] = wbhh[g2*260 + bid*4 + dl2];
  }
  int ds = dsteps[0]; if (ds < 1) ds = 1;
  float sb = logf(fmaxf(1.f, (float)surprise[0]));
  float vgb_sb = vgb[0] + sb;
  float will_r = 0.f, cost_r = 0.f;
  const float costfac = 0.12f/2048.f;
  float* pf   = ws + OFF_PF;
  float* latb = ws + OFF_LATB;
  float* hmb  = ws + OFF_HMB;
  int p = 0;
  __syncthreads();
  for (int t = 0; t < 2048; ++t) {
    const float* lsrc = pf + t*3120;      // regular cached loads (from k2, kernel boundary)
    for (int idx = tid; idx < 780; idx += 256) {
      int i = idx / 65, j = idx - i*65;
      ((float4*)&lat[i][0])[j] = ((const float4*)(lsrc + i*260))[j];
    }
    if (t == 0) {
      for (int idx = tid; idx < 780; idx += 256) {
        int i = idx / 65, j = idx - i*65;
        ((float4*)&hm[i][0])[j] = ((const float4*)(h_mono + i*260))[j];
      }
    } else {
      const float* hs = hmb + p*3120;
      for (int idx = tid; idx < 3120; idx += 256) {
        int i = idx / 260, dd = idx - i*260;
        hm[i][dd] = ld_wt(hs + idx);
      }
    }
    __syncthreads();
    for (int s = 0; s < ds; ++s) {
      // vol (redundant in every WG, identical results)
      if (grp < 12) {
        int i = grp;
        float pv = 0;
        const float* lp = &lat[i][k0];
        #pragma unroll
        for (int kk = 0; kk < 20; ++kk) pv += vg_l[k0+kk]*lp[kk];
        #pragma unroll
        for (int m = 8; m; m >>= 1) pv += __shfl_xor(pv, m);
        if (l16 == 0) vol_l[i] = 1.f/(1.f + expf(-(pv + vgb_sb)));
      }
      __syncthreads();
      if (tid == 0) {
        float vs = 0;
        #pragma unroll
        for (int i = 0; i < 12; ++i) vs += vol_l[i];
        float vm = vs * (1.f/12.f);
        will_r += vm;
        cost_r += vm * costfac;
      }
      // grucell partial dots for our 4 dims
      #pragma unroll
      for (int i3 = 0; i3 < 3; ++i3) {
        int i = iq*3 + i3;
        float a0=0,a1=0,a2=0,b0=0,b1=0,b2=0;
        const float* lp = &lat[i][k0];
        const float* hp = &hm[i][k0];
        #pragma unroll
        for (int kk = 0; kk < 20; ++kk) {
          float lv = lp[kk], hv = hp[kk];
          a0 += wi[0][kk]*lv; a1 += wi[1][kk]*lv; a2 += wi[2][kk]*lv;
          b0 += wh[0][kk]*hv; b1 += wh[1][kk]*hv; b2 += wh[2][kk]*hv;
        }
        #pragma unroll
        for (int m = 8; m; m >>= 1) {
          a0 += __shfl_xor(a0,m); a1 += __shfl_xor(a1,m); a2 += __shfl_xor(a2,m);
          b0 += __shfl_xor(b0,m); b1 += __shfl_xor(b1,m); b2 += __shfl_xor(b2,m);
        }
        if (l16 == 0) {
          gl6[dl][i][0]=a0; gl6[dl][i][1]=a1; gl6[dl][i][2]=a2;
          gl6[dl][i][3]=b0; gl6[dl][i][4]=b1; gl6[dl][i][5]=b2;
        }
      }
      __syncthreads();
      if (tid < 48) {
        int dl2 = tid / 12, i = tid - dl2*12;
        int dd = bid*4 + dl2;
        float xr = gl6[dl2][i][0] + bih_l[dl2][0];
        float xz = gl6[dl2][i][1] + bih_l[dl2][1];
        float xn = gl6[dl2][i][2] + bih_l[dl2][2];
        float hr = gl6[dl2][i][3] + bhh_l[dl2][0];
        float hz = gl6[dl2][i][4] + bhh_l[dl2][1];
        float hn = gl6[dl2][i][5] + bhh_l[dl2][2];
        float rg = 1.f/(1.f + expf(-(xr+hr)));
        float zg = 1.f/(1.f + expf(-(xz+hz)));
        float ng = tanhf(xn + rg*hn);
        float hmold = hm[i][dd];
        float hmnew = (1.f - zg)*ng + zg*hmold;
        float latnew = lat[i][dd] + hmnew * vol_l[i];
        st_wt(hmb + (p^1)*3120 + i*260 + dd, hmnew);
        st_wt(latb + (p^1)*3120 + i*260 + dd, latnew);
        if (s == ds-1) {
          pf[(t*12 + i)*260 + dd] = latnew;   // latf overlays p_f[t] (read 3 rounds earlier)
          if (t == 2047) out[OUT_HM + i*260 + dd] = hmnew;
        }
      }
      post_and_wait(flags, bid, t*ds + s + 1, (t == 2047) && (s == ds-1));
      p ^= 1;
      if (s < ds-1) {
        const float* ls2 = latb + p*3120;
        const float* hs2 = hmb + p*3120;
        for (int idx = tid; idx < 3120; idx += 256) {
          int i = idx / 260, dd = idx - i*260;
          lat[i][dd] = ld_wt(ls2 + idx);
          hm[i][dd]  = ld_wt(hs2 + idx);
        }
        __syncthreads();
      }
    }
  }
  if (bid == 0 && tid == 0) {
    out[OUT_DS]   = (float)dsteps[0];
    out[OUT_DS+1] = cost_r;
    out[OUT_DS+2] = will_r / (2048.f * (float)ds);
  }
}

// ============ K4: per-t tail (attention + pfc + LN + GELU), parallel over t ============
__global__ __launch_bounds__(256) void k4_tail(
    const float* __restrict__ rel_vals, const float* __restrict__ pfc_b,
    const float* __restrict__ pfc_g, const float* __restrict__ pfc_beta,
    float* __restrict__ ws) {
  int t = blockIdx.x, tid = threadIdx.x;
  int tg = tid >> 4, l16 = tid & 15;
  __shared__ float lat[12][260];
  __shared__ float sc[12][280];
  __shared__ float ctx[12][260];
  __shared__ float zb[12][260];
  __shared__ float qinv[12];
  __shared__ float mu[12], rstd[12];
  const float* lsrc = ws + OFF_PF + t*3120;   // latf
  for (int idx = tid; idx < 780; idx += 256)
    ((float4*)lat)[idx] = ((const float4*)lsrc)[idx];
  __syncthreads();
  if (tg < 12) {
    float ss = 0;
    for (int k = l16; k < 260; k += 16) { float v = lat[tg][k]; ss += v*v; }
    #pragma unroll
    for (int m = 8; m; m >>= 1) ss += __shfl_xor(ss, m);
    if (l16 == 0) qinv[tg] = 1.f / fmaxf(sqrtf(ss), 1e-12f);
  }
  __syncthreads();
  for (int r = tid; r < 280; r += 256) {
    const float* kn = ws + OFF_KEYS + r*260;
    float acc[12];
    #pragma unroll
    for (int i = 0; i < 12; ++i) acc[i] = 0.f;
    for (int k = 0; k < 260; ++k) {
      float kv = kn[k];
      #pragma unroll
      for (int i = 0; i < 12; ++i) acc[i] += lat[i][k]*kv;
    }
    #pragma unroll
    for (int i = 0; i < 12; ++i) sc[i][r] = acc[i]*qinv[i];
  }
  __syncthreads();
  if (tg < 12) {
    float mx = -1e30f;
    for (int r = l16; r < 280; r += 16) mx = fmaxf(mx, sc[tg][r]);
    #pragma unroll
    for (int m = 8; m; m >>= 1) mx = fmaxf(mx, __shfl_xor(mx, m));
    float sum = 0;
    for (int r = l16; r < 280; r += 16) { float e = expf(sc[tg][r]-mx); sc[tg][r] = e; sum += e; }
    #pragma unroll
    for (int m = 8; m; m >>= 1) sum += __shfl_xor(sum, m);
    float inv = 1.f/sum;
    for (int r = l16; r < 280; r += 16) sc[tg][r] *= inv;
  }
  __syncthreads();
  for (int dd = tid; dd < 260; dd += 256) {
    float acc[12];
    #pragma unroll
    for (int i = 0; i < 12; ++i) acc[i] = 0.f;
    for (int r = 0; r < 280; ++r) {
      float rv = rel_vals[r*260 + dd];
      #pragma unroll
      for (int i = 0; i < 12; ++i) acc[i] += sc[i][r]*rv;
    }
    #pragma unroll
    for (int i = 0; i < 12; ++i) ctx[i][dd] = acc[i];
  }
  __syncthreads();
  for (int dd = tid; dd < 260; dd += 256) {
    float acc[12];
    float pb = pfc_b[dd];
    #pragma unroll
    for (int i = 0; i < 12; ++i) acc[i] = pb;
    const float* wt = ws + OFF_PFCT;
    for (int k = 0; k < 260; ++k) {
      float w1 = wt[k*260 + dd];
      #pragma unroll
      for (int i = 0; i < 12; ++i) acc[i] += lat[i][k]*w1;
    }
    for (int k = 0; k < 260; ++k) {
      float w2 = wt[(260+k)*260 + dd];
      #pragma unroll
      for (int i = 0; i < 12; ++i) acc[i] += ctx[i][k]*w2;
    }
    #pragma unroll
    for (int i = 0; i < 12; ++i) zb[i][dd] = acc[i];
  }
  __syncthreads();
  if (tg < 12) {
    float s1 = 0, s2 = 0;
    for (int k = l16; k < 260; k += 16) { float v = zb[tg][k]; s1 += v; s2 += v*v; }
    #pragma unroll
    for (int m = 8; m; m >>= 1) { s1 += __shfl_xor(s1,m); s2 += __shfl_xor(s2,m); }
    if (l16 == 0) {
      float mm = s1*(1.f/260.f);
      mu[tg] = mm;
      rstd[tg] = rsqrtf(s2*(1.f/260.f) - mm*mm + 1e-5f);
    }
  }
  __syncthreads();
  for (int dd = tid; dd < 260; dd += 256) {
    float g = pfc_g[dd], b = pfc_beta[dd];
    #pragma unroll
    for (int i = 0; i < 12; ++i) {
      float v = (zb[i][dd]-mu[i])*rstd[i]*g + b;
      float ge = 0.5f*v*(1.f + erff(v*0.70710678118654752f));
      ws[OFF_OUTS + (i*2048 + t)*260 + dd] = ge;
    }
  }
}

// ============ K5: fused LN + logits GEMM (8 rows per WG) ============
__global__ __launch_bounds__(256) void k5_logits(
    const float* __restrict__ on_g, const float* __restrict__ on_b,
    const float* __restrict__ gain, float* __restrict__ ws,
    float* __restrict__ out) {
  int bid = blockIdx.x, tid = threadIdx.x;
  __shared__ float nl[8][260];
  __shared__ float red[4];
  float gn = gain[0];
  float og0 = on_g[tid], ob0 = on_b[tid];
  float og1 = (tid < 4) ? on_g[256+tid] : 0.f;
  float ob1 = (tid < 4) ? on_b[256+tid] : 0.f;
  for (int ii = 0; ii < 8; ++ii) {
    int m = bid*8 + ii;
    const float* row = ws + OFF_OUTS + m*260;
    float v0 = row[tid];
    float v1 = (tid < 4) ? row[256+tid] : 0.f;
    float s1 = block_sum256(v0 + v1, red);
    float s2 = block_sum256(v0*v0 + v1*v1, red);
    float mm = s1*(1.f/260.f);
    float rs = rsqrtf(s2*(1.f/260.f) - mm*mm + 1e-5f);
    nl[ii][tid] = (v0-mm)*rs*og0 + ob0;
    if (tid < 4) nl[ii][256+tid] = (v1-mm)*rs*og1 + ob1;
  }
  __syncthreads();
  float acc[8];
  #pragma unroll
  for (int ii = 0; ii < 8; ++ii) acc[ii] = 0.f;
  const float* st = ws + OFF_SNT;
  for (int k = 0; k < 260; ++k) {
    float wv = st[k*256 + tid];
    #pragma unroll
    for (int ii = 0; ii < 8; ++ii) acc[ii] += nl[ii][k]*wv;
  }
  #pragma unroll
  for (int ii = 0; ii < 8; ++ii)
    out[(bid*8 + ii)*256 + tid] = acc[ii]*gn;
}

// ============================ launch ============================
extern "C" void kernel_launch(void* const* d_in, const int* in_sizes, int n_in,
                              void* d_out, int out_size, void* d_ws, size_t ws_size,
                              hipStream_t stream) {
  const int*   x        = (const int*)  d_in[0];
  const float* h_f      = (const float*)d_in[1];
  const float* h_mono   = (const float*)d_in[2];
  const int*   surprise = (const int*)  d_in[3];
  const int*   dsteps   = (const int*)  d_in[4];
  const float* soma_w   = (const float*)d_in[5];
  const float* gWih     = (const float*)d_in[6];
  const float* gWhh     = (const float*)d_in[7];
  const float* gbih     = (const float*)d_in[8];
  const float* gbhh     = (const float*)d_in[9];
  const float* wWih     = (const float*)d_in[10];
  const float* wWhh     = (const float*)d_in[11];
  const float* wbih     = (const float*)d_in[12];
  const float* wbhh     = (const float*)d_in[13];
  const float* vgW      = (const float*)d_in[14];
  const float* vgb      = (const float*)d_in[15];
  const float* rel_keys = (const float*)d_in[16];
  const float* rel_vals = (const float*)d_in[17];
  const float* pfc_W    = (const float*)d_in[18];
  const float* pfc_b    = (const float*)d_in[19];
  const float* pfc_g    = (const float*)d_in[20];
  const float* pfc_beta = (const float*)d_in[21];
  const float* on_g     = (const float*)d_in[22];
  const float* on_b     = (const float*)d_in[23];
  const float* gain     = (const float*)d_in[24];
  float* out = (float*)d_out;
  float* ws  = (float*)d_ws;
  if (ws_size < (size_t)WS_FLOATS * sizeof(float)) return;  // fail loudly (poisoned out)
  int* flags1 = (int*)(ws + OFF_OUTS);          // dead region during scans
  int* flags2 = flags1 + NB1*FLAG_STRIDE;
  hipMemsetAsync(flags1, 0, NFLAG_INTS*sizeof(int), stream);
  k0_prep  <<<1312, 256, 0, stream>>>(soma_w, gWih, gbih, rel_keys, pfc_W, ws);
  k2_scan1 <<<NB1, 256, 0, stream>>>(x, h_f, gWhh, gbhh, ws, flags1, out);
  k3_scan2 <<<NB1, 256, 0, stream>>>(h_mono, wWih, wWhh, wbih, wbhh, vgW, vgb,
                                     surprise, dsteps, ws, flags2, out);
  k4_tail  <<<2048, 256, 0, stream>>>(rel_vals, pfc_b, pfc_g, pfc_beta, ws);
  k5_logits<<<3072, 256, 0, stream>>>(on_g, on_b, gain, ws, out);
}